// Round 9
// baseline (51.586 us; speedup 1.0000x reference)
//
#include <hip/hip_runtime.h>
#include <hip/hip_bf16.h>

typedef short bf16x8 __attribute__((ext_vector_type(8)));
typedef float f32x16 __attribute__((ext_vector_type(16)));

#define NB 8
#define NPTS 8192
#define NSET (NB * NPTS)
#define CHUNK_BYTES 16384   // 16 col-tiles of 1KB
#define NCHUNK 8            // 128 tiles per col-half

static __device__ __forceinline__ short bfbits(float x) {
    __hip_bfloat16 h = __float2bfloat16(x);  // RNE
    return *reinterpret_cast<short*>(&h);
}
static __device__ __forceinline__ float bfval(float x) {
    __hip_bfloat16 h = __float2bfloat16(x);
    return __bfloat162float(h);
}

// Per point, emit K=16 bf16 row-features (A) and col-features (B) so that
// dot(A_t, B_p) = |t|^2 + |p|^2 - 2 t.p  (hi/lo bf16 split).
// B in FRAGMENT ORDER per 32-point tile (tile*1024B, khalf-major): staging
// and ds_read_b128 are linear lane*16 -> conflict-free.
__global__ __launch_bounds__(256) void pack2_kernel(
    const float* __restrict__ target, const float* __restrict__ pred,
    short* __restrict__ tA, short* __restrict__ tB,
    short* __restrict__ pA, short* __restrict__ pB) {
    int gi = blockIdx.x * 256 + threadIdx.x;
    int second = gi >= NSET;
    int i = second ? gi - NSET : gi;
    const float* pts = second ? pred : target;
    short* A = second ? pA : tA;
    short* B = second ? pB : tB;

    float x = pts[3 * i + 0], y = pts[3 * i + 1], z = pts[3 * i + 2];
    float n2 = x * x + y * y + z * z;

    float xh = bfval(x), yh = bfval(y), zh = bfval(z), nh = bfval(n2);
    short xhb = bfbits(x), yhb = bfbits(y), zhb = bfbits(z), nhb = bfbits(n2);
    short xlb = bfbits(x - xh), ylb = bfbits(y - yh), zlb = bfbits(z - zh), nlb = bfbits(n2 - nh);
    short one = bfbits(1.0f);
    short mxh = bfbits(-2.0f * xh), myh = bfbits(-2.0f * yh), mzh = bfbits(-2.0f * zh);
    short mxl = bfbits(-2.0f * __bfloat162float(*(__hip_bfloat16*)&xlb));
    short myl = bfbits(-2.0f * __bfloat162float(*(__hip_bfloat16*)&ylb));
    short mzl = bfbits(-2.0f * __bfloat162float(*(__hip_bfloat16*)&zlb));

    // A k=0..15: [1,1,n2h,n2l, xh,xh,xl, yh,yh,yl, zh,zh,zl, 0,0,0]
    bf16x8 a0, a1, b0, b1;
    a0[0] = one; a0[1] = one; a0[2] = nhb; a0[3] = nlb;
    a0[4] = xhb; a0[5] = xhb; a0[6] = xlb; a0[7] = yhb;
    a1[0] = yhb; a1[1] = ylb; a1[2] = zhb; a1[3] = zhb;
    a1[4] = zlb; a1[5] = 0;   a1[6] = 0;   a1[7] = 0;
    // B k=0..15: [n2h,n2l,1,1, -2xh,-2xl,-2xh, -2yh,-2yl,-2yh, -2zh,-2zl,-2zh, 0,0,0]
    b0[0] = nhb; b0[1] = nlb; b0[2] = one; b0[3] = one;
    b0[4] = mxh; b0[5] = mxl; b0[6] = mxh; b0[7] = myh;
    b1[0] = myl; b1[1] = myh; b1[2] = mzh; b1[3] = mzl;
    b1[4] = mzh; b1[5] = 0;   b1[6] = 0;   b1[7] = 0;

    *reinterpret_cast<bf16x8*>(&A[(size_t)i * 16])     = a0;
    *reinterpret_cast<bf16x8*>(&A[(size_t)i * 16 + 8]) = a1;

    int bb = i >> 13;                 // batch
    int pi = i & (NPTS - 1);
    int tile = pi >> 5, l = pi & 31;
    short* Bp = B + (size_t)bb * NPTS * 16 + tile * 512;
    *reinterpret_cast<bf16x8*>(Bp + l * 8)       = b0;   // khalf 0
    *reinterpret_cast<bf16x8*>(Bp + 256 + l * 8) = b1;   // khalf 1
}

// Stage one 16KB chunk (16 tiles) global->LDS; each wave copies 4x1KB.
static __device__ __forceinline__ void stage_chunk(char* ldsbase, const char* gsrc,
                                                   int wave, int lane) {
#pragma unroll
    for (int s = 0; s < 4; ++s) {
        int off = s * 4096 + wave * 1024;
        __builtin_amdgcn_global_load_lds(
            (const __attribute__((address_space(1))) unsigned int*)(gsrc + off + lane * 16),
            (__attribute__((address_space(3))) unsigned int*)(ldsbase + off),
            16, 0, 0);
    }
}

// lane-merge: combine two row-registers across lane-pairs (xor m).
#define MERGE(dst, u, v, m) {                       \
    float _own = (lane & (m)) ? (v) : (u);          \
    float _sel = (lane & (m)) ? (u) : (v);          \
    dst = fminf(_own, __shfl_xor(_sel, (m))); }

// Grid 1024: dir x 8 batches x 32 rowgroups(256 rows) x 2 col-halves.
// 4 blocks/CU (16 waves) for latency hiding. Each block stores its 256
// partial row-mins (min over its col-half) to rowmin[dir][colhalf][...]:
// no atomics, no init, no fills anywhere.
__global__ __launch_bounds__(256, 4) void chamfer_mfma_kernel(
    const short* __restrict__ targA, const short* __restrict__ targB,
    const short* __restrict__ predA, const short* __restrict__ predB,
    float* __restrict__ rowmin)   // [2 dir][2 half][NSET]
{
    __shared__ __align__(16) char smem[2][CHUNK_BYTES];

    const int bid  = blockIdx.x;
    const int pass = bid >> 9;             // 0: rows=target, 1: rows=pred
    const int b    = (bid >> 6) & 7;
    const int rowgrp  = (bid >> 1) & 31;   // 32 groups of 256 rows
    const int colhalf = bid & 1;           // 2 halves of 4096 cols
    const int wave = threadIdx.x >> 6;
    const int lane = threadIdx.x & 63;
    const int l31  = lane & 31, h = lane >> 5;

    const short* Af = pass ? predA : targA;
    const short* Bf = pass ? targB : predB;

    const int row0 = rowgrp * 256 + wave * 64;
    const short* abase = Af + ((size_t)(b * NPTS + row0 + l31)) * 16 + h * 8;
    bf16x8 a0 = *reinterpret_cast<const bf16x8*>(abase);            // rows +0..31
    bf16x8 a1 = *reinterpret_cast<const bf16x8*>(abase + 32 * 16);  // rows +32..63

    const char* bsrc = (const char*)Bf + (size_t)b * NPTS * 32
                     + (size_t)colhalf * (NPTS / 2) * 32;  // 128KB frag-ordered half

    float acc0[16], acc1[16];
#pragma unroll
    for (int r = 0; r < 16; ++r) { acc0[r] = 3.4e38f; acc1[r] = 3.4e38f; }

    const f32x16 z = {0.f,0.f,0.f,0.f, 0.f,0.f,0.f,0.f, 0.f,0.f,0.f,0.f, 0.f,0.f,0.f,0.f};

    stage_chunk(smem[0], bsrc, wave, lane);

    for (int c = 0; c < NCHUNK; ++c) {
        __syncthreads();   // chunk c staged (vmcnt drained at barrier)
        if (c + 1 < NCHUNK)
            stage_chunk(smem[(c + 1) & 1], bsrc + (size_t)(c + 1) * CHUNK_BYTES, wave, lane);
        const char* bufc = smem[c & 1];
#pragma unroll
        for (int t = 0; t < 16; t += 2) {
            bf16x8 bA = *reinterpret_cast<const bf16x8*>(bufc + t * 1024 + lane * 16);
            bf16x8 bB = *reinterpret_cast<const bf16x8*>(bufc + t * 1024 + 1024 + lane * 16);
            f32x16 ca = __builtin_amdgcn_mfma_f32_32x32x16_bf16(a0, bA, z, 0, 0, 0);
            f32x16 cb = __builtin_amdgcn_mfma_f32_32x32x16_bf16(a0, bB, z, 0, 0, 0);
#pragma unroll
            for (int r = 0; r < 16; ++r)
                acc0[r] = fminf(fminf(acc0[r], ca[r]), cb[r]);  // -> v_min3_f32
            f32x16 da = __builtin_amdgcn_mfma_f32_32x32x16_bf16(a1, bA, z, 0, 0, 0);
            f32x16 db = __builtin_amdgcn_mfma_f32_32x32x16_bf16(a1, bB, z, 0, 0, 0);
#pragma unroll
            for (int r = 0; r < 16; ++r)
                acc1[r] = fminf(fminf(acc1[r], da[r]), db[r]);
        }
    }

    // log-merge: 32 regs x 32-lane col-min -> each lane holds one row's min
    // over this col-half.
#pragma unroll
    for (int k = 0; k < 8; ++k) { MERGE(acc0[k], acc0[2*k], acc0[2*k+1], 1); }
#pragma unroll
    for (int k = 0; k < 8; ++k) { MERGE(acc1[k], acc1[2*k], acc1[2*k+1], 1); }
#pragma unroll
    for (int k = 0; k < 4; ++k) { MERGE(acc0[k], acc0[2*k], acc0[2*k+1], 2); }
#pragma unroll
    for (int k = 0; k < 4; ++k) { MERGE(acc1[k], acc1[2*k], acc1[2*k+1], 2); }
#pragma unroll
    for (int k = 0; k < 2; ++k) { MERGE(acc0[k], acc0[2*k], acc0[2*k+1], 4); }
#pragma unroll
    for (int k = 0; k < 2; ++k) { MERGE(acc1[k], acc1[2*k], acc1[2*k+1], 4); }
    MERGE(acc0[0], acc0[0], acc0[1], 8);
    MERGE(acc1[0], acc1[0], acc1[1], 8);
    float fin;
    MERGE(fin, acc0[0], acc1[0], 16);
    // row(lane): lane bits {0,1}->row bits{0,1}, lane5->+4, lane2->+8,
    // lane3->+16, lane4->+32 (verified r7/r8, passed)
    int row = (lane & 3) + 4 * ((lane >> 5) & 1) + 8 * ((lane >> 2) & 1)
            + 16 * ((lane >> 3) & 1) + 32 * ((lane >> 4) & 1);
    rowmin[((size_t)(pass * 2 + colhalf)) * NSET + b * NPTS + row0 + row] = fin;
}

// min the two col-halves, sum -> one partial per block (no atomics).
__global__ __launch_bounds__(256) void reduce_kernel(const float* __restrict__ rowmin,
                                                     float* __restrict__ partials) {
    const int stride = gridDim.x * 256;
    float v = 0.0f;
    for (int i = blockIdx.x * 256 + threadIdx.x; i < 2 * NSET; i += stride) {
        int d = i >> 16;   // NSET = 65536
        size_t base = (size_t)i + (size_t)d * NSET;
        v += fminf(rowmin[base], rowmin[base + NSET]);
    }
#pragma unroll
    for (int o = 32; o > 0; o >>= 1) v += __shfl_xor(v, o);
    __shared__ float wpart[4];
    if ((threadIdx.x & 63) == 0) wpart[threadIdx.x >> 6] = v;
    __syncthreads();
    if (threadIdx.x == 0)
        partials[blockIdx.x] = wpart[0] + wpart[1] + wpart[2] + wpart[3];
}

// Single block: sum 128 partials, scale, store.
__global__ __launch_bounds__(128) void final_kernel(const float* __restrict__ partials,
                                                    float* __restrict__ out) {
    __shared__ float wpart[2];
    float v = partials[threadIdx.x];
#pragma unroll
    for (int o = 32; o > 0; o >>= 1) v += __shfl_xor(v, o);
    if ((threadIdx.x & 63) == 0) wpart[threadIdx.x >> 6] = v;
    __syncthreads();
    if (threadIdx.x == 0)
        out[0] = (wpart[0] + wpart[1]) * (1.0f / (float)NSET);
}

extern "C" void kernel_launch(void* const* d_in, const int* in_sizes, int n_in,
                              void* d_out, int out_size, void* d_ws, size_t ws_size,
                              hipStream_t stream) {
    const float* pred   = (const float*)d_in[0];   // [8,8192,3]
    const float* target = (const float*)d_in[1];   // [8,8192,3]
    float* out = (float*)d_out;

    char* ws = (char*)d_ws;
    float* rowmin   = (float*)ws;                       // 4*NSET floats = 1MB
    float* partials = rowmin + (size_t)4 * NSET;        // 128 floats
    short* tA = (short*)(ws + (size_t)4 * NSET * 4 + 4096);  // each 2 MB
    short* tB = tA + (size_t)NSET * 16;
    short* pA = tB + (size_t)NSET * 16;
    short* pB = pA + (size_t)NSET * 16;

    pack2_kernel<<<2 * NSET / 256, 256, 0, stream>>>(target, pred, tA, tB, pA, pB);

    chamfer_mfma_kernel<<<1024, 256, 0, stream>>>(tA, tB, pA, pB, rowmin);

    reduce_kernel<<<128, 256, 0, stream>>>(rowmin, partials);
    final_kernel<<<1, 128, 0, stream>>>(partials, out);
}